// Round 2
// baseline (145.366 us; speedup 1.0000x reference)
//
#include <hip/hip_runtime.h>

#define NSTEPS 10
constexpr int B_DIM = 256, T_DIM = 8192, D_DIM = 5;
constexpr int TILE  = 1024;   // items per block
constexpr int BLOCK = 256;    // threads per block
constexpr long long GATE_N = (long long)B_DIM * 2 * T_DIM;   // 4,194,304
constexpr long long EXT_N  = GATE_N * D_DIM;                 // 20,971,520

// 10-step scan in f64 (bit-identical to round-1 numerics), f32 epilogue.
__device__ __forceinline__ float scan_score(double v0, double v1, double v2, double v3, double v4,
                                            const double* __restrict__ w) {
    float h[NSTEPS];
#pragma unroll
    for (int s = 0; s < NSTEPS; ++s) {
        double res = v0 * w[0];
        res = fma(v1, w[1], res);
        res = fma(v2, w[2], res);
        res = fma(v3, w[3], res);
        res = fma(v4, w[4], res);
        h[s] = (float)res;
        double q = floor(res * 0.1);
        double m = fma(q, -10.0, res);
        m = (m < 0.0)   ? m + 10.0 : m;
        m = (m >= 10.0) ? m - 10.0 : m;
        v4 = v3; v3 = v2; v2 = v1; v1 = v0; v0 = m;
    }
    float mean = 0.f;
#pragma unroll
    for (int s = 0; s < NSTEPS; ++s) mean += h[s];
    mean *= 0.1f;
    float ssd = 0.f;
#pragma unroll
    for (int s = 0; s < NSTEPS; ++s) { float d = h[s] - mean; ssd = fmaf(d, d, ssd); }
    float sd = sqrtf(ssd * (1.0f / 9.0f));
    return 1.0f / (1.0f + sd);
}

__global__ __launch_bounds__(BLOCK) void temple_gate_kernel(
    const float* __restrict__ x, const float* __restrict__ temple,
    const float* __restrict__ breath, float* __restrict__ out) {
    __shared__ float lds[TILE * D_DIM];   // 20 KB

    const int k  = threadIdx.x;
    const int b  = blockIdx.x >> 3;        // 8 tiles per row
    const int t0 = (blockIdx.x & 7) * TILE;

    // ---- uniform scalars: mode + folded weights (every thread, f64, L2-hot) ----
    double s = 0.0;
    for (int d = 0; d < 5; ++d) s += (double)x[d];
    s = s / 5.0;
    double seed  = s - floor(s);
    double chaos = 3.5699456 * seed * (1.0 - seed);
    const int mode = (chaos > 0.7) ? 0 : ((chaos > 0.4) ? 1 : 2);
    double wm[5], wx[5];
#pragma unroll
    for (int d = 0; d < 5; ++d) {
        double a = 0.0, c = 0.0;
#pragma unroll
        for (int r = 0; r < 4; ++r) {
            double tv = (double)temple[r * 5 + d];
            a += (double)breath[r]     * tv;   // breath_main = breath[0:4]
            c += (double)breath[r + 1] * tv;   // breath_mirror = breath[1:5]
        }
        wm[d] = a; wx[d] = c;
    }
    if (blockIdx.x == 0 && k == 0) out[GATE_N + EXT_N] = (float)mode;

    // ---- coalesced float4 tile load: 1280 float4 = 1024 items ----
    const long long srcBase = ((long long)b * T_DIM + t0) * D_DIM;
    const float4* __restrict__ src = (const float4*)(x + srcBase);
    float4 r0 = src[k],       r1 = src[k + 256], r2 = src[k + 512],
           r3 = src[k + 768], r4 = src[k + 1024];

    float4* l4 = (float4*)lds;
    l4[k] = r0; l4[k + 256] = r1; l4[k + 512] = r2; l4[k + 768] = r3; l4[k + 1024] = r4;

    float* gate = out;
    float* ext  = out + GATE_N;
    const long long rowBase = (long long)b * (2 * T_DIM);

    // ---- main ext: pure copy, coalesced float4 from registers ----
    {
        float4* dst = (float4*)(ext + (rowBase + t0) * D_DIM);
        dst[k] = r0; dst[k + 256] = r1; dst[k + 512] = r2; dst[k + 768] = r3; dst[k + 1024] = r4;
    }
    // ---- mirror ext, modes 0/2: same layout (+T), value transform for mode 0 ----
    if (mode == 0) {
        float4* dst = (float4*)(ext + (rowBase + T_DIM + t0) * D_DIM);
        float4 m0 = make_float4(9.f - r0.x, 9.f - r0.y, 9.f - r0.z, 9.f - r0.w);
        float4 m1 = make_float4(9.f - r1.x, 9.f - r1.y, 9.f - r1.z, 9.f - r1.w);
        float4 m2 = make_float4(9.f - r2.x, 9.f - r2.y, 9.f - r2.z, 9.f - r2.w);
        float4 m3 = make_float4(9.f - r3.x, 9.f - r3.y, 9.f - r3.z, 9.f - r3.w);
        float4 m4 = make_float4(9.f - r4.x, 9.f - r4.y, 9.f - r4.z, 9.f - r4.w);
        dst[k] = m0; dst[k + 256] = m1; dst[k + 512] = m2; dst[k + 768] = m3; dst[k + 1024] = m4;
    } else if (mode == 2) {
        float4* dst = (float4*)(ext + (rowBase + T_DIM + t0) * D_DIM);
        dst[k] = r0; dst[k + 256] = r1; dst[k + 512] = r2; dst[k + 768] = r3; dst[k + 1024] = r4;
    }

    __syncthreads();

    // ---- mirror ext, mode 1 (flip along t): reversed-item tile is still a
    //      contiguous float4-aligned destination; assemble from LDS ----
    if (mode == 1) {
        float4* dst = (float4*)(ext + (rowBase + 2 * T_DIM - t0 - TILE) * D_DIM);
#pragma unroll
        for (int j = 0; j < 5; ++j) {
            const int q = k + j * 256;       // dest float4 index in tile
            const int f = q * 4;             // dest flat float index
            float v[4];
#pragma unroll
            for (int c = 0; c < 4; ++c) {
                const int fc = f + c;
                const int fi = fc / 5, d = fc - fi * 5;   // dest item, dim
                v[c] = lds[(TILE - 1 - fi) * 5 + d];      // src item = TILE-1-fi
            }
            dst[q] = make_float4(v[0], v[1], v[2], v[3]);
        }
    }

    // ---- scans: 4 items per thread from LDS, gates stored as float4 ----
    {
        const int itBase = 4 * k;
        float gm[4], gx[4];
#pragma unroll
        for (int j = 0; j < 4; ++j) {
            const float* p = &lds[(itBase + j) * 5];
            double v0 = p[0], v1 = p[1], v2 = p[2], v3 = p[3], v4 = p[4];
            gm[j] = scan_score(v0, v1, v2, v3, v4, wm);
            if (mode == 0) { v0 = 9.0 - v0; v1 = 9.0 - v1; v2 = 9.0 - v2; v3 = 9.0 - v3; v4 = 9.0 - v4; }
            gx[j] = scan_score(v0, v1, v2, v3, v4, wx);
        }
        ((float4*)(gate + rowBase + t0))[k] = make_float4(gm[0], gm[1], gm[2], gm[3]);
        if (mode == 1) {
            // dest items descend: store reversed float4 at mirrored index
            ((float4*)(gate + rowBase + 2 * T_DIM - t0 - TILE))[255 - k] =
                make_float4(gx[3], gx[2], gx[1], gx[0]);
        } else {
            ((float4*)(gate + rowBase + T_DIM + t0))[k] = make_float4(gx[0], gx[1], gx[2], gx[3]);
        }
    }
}

extern "C" void kernel_launch(void* const* d_in, const int* in_sizes, int n_in,
                              void* d_out, int out_size, void* d_ws, size_t ws_size,
                              hipStream_t stream) {
    const float* x      = (const float*)d_in[0];   // (256, 8192, 5) f32
    const float* temple = (const float*)d_in[1];   // (4, 5) f32
    const float* breath = (const float*)d_in[2];   // (5,) f32
    float* out = (float*)d_out;                    // [gate | extended_x | mode_code]

    const int blocks = (B_DIM * T_DIM) / TILE;     // 2048
    temple_gate_kernel<<<blocks, BLOCK, 0, stream>>>(x, temple, breath, out);
}